// Round 18
// baseline (179.248 us; speedup 1.0000x reference)
//
#include <hip/hip_runtime.h>
#include <hip/hip_bf16.h>
#include <stdint.h>

// Problem constants (B,S,F,H,D) = (4, 2048, 1024, 16, 64)
#define B_ 4
#define S_ 2048
#define F_ 1024
#define H_ 16
#define D_ 64
#define M_ (B_*S_)
#define OUTHALF ((size_t)B_*S_*F_)
#define KVB 64
#define QBLK 128   // 8 waves x 16 q-rows

typedef __attribute__((ext_vector_type(4))) float f32x4;
typedef __attribute__((ext_vector_type(8))) short bf16x8;

__device__ __forceinline__ short f2bf(float f) {
  __hip_bfloat16 h = __float2bfloat16(f);   // RNE
  return *reinterpret_cast<short*>(&h);
}

__device__ __forceinline__ void gl2lds16(const short* g, short* l) {
  __builtin_amdgcn_global_load_lds(
      (const __attribute__((address_space(1))) uint32_t*)g,
      (__attribute__((address_space(3))) uint32_t*)l, 16, 0, 0);
}

// counted-vmcnt barrier: leave N vmem ops in flight across the barrier (T4)
#define VMCNT_BAR(N)                                            \
  do {                                                          \
    asm volatile("s_waitcnt vmcnt(" #N ")" ::: "memory");       \
    __builtin_amdgcn_s_barrier();                               \
    asm volatile("" ::: "memory");                              \
  } while (0)

// ---------------- 1. Fused prep: X fp32->bf16  +  W^T bf16 ----------------
__global__ __launch_bounds__(256) void prep(
    const float* __restrict__ X, short* __restrict__ Xb,
    const float* __restrict__ wq, const float* __restrict__ wk, const float* __restrict__ wv,
    short* __restrict__ tq, short* __restrict__ tk, short* __restrict__ tv) {
  __shared__ float tile[32][33];
  const int bid = blockIdx.x;
  const int tid = threadIdx.x;
  if (bid < (M_ * F_) / (256 * 8)) {
    int i = (bid * 256 + tid) * 8;
    f32x4 a = *(const f32x4*)(X + i);
    f32x4 b = *(const f32x4*)(X + i + 4);
    bf16x8 o;
    o[0]=f2bf(a[0]); o[1]=f2bf(a[1]); o[2]=f2bf(a[2]); o[3]=f2bf(a[3]);
    o[4]=f2bf(b[0]); o[5]=f2bf(b[1]); o[6]=f2bf(b[2]); o[7]=f2bf(b[3]);
    *(bf16x8*)(Xb + i) = o;
    return;
  }
  const int b2 = bid - (M_ * F_) / (256 * 8);
  const int z = b2 >> 10;
  const int rem = b2 & 1023;
  const int bx = rem & 31, by = rem >> 5;
  const float* W = z == 0 ? wq : (z == 1 ? wk : wv);
  short* T = z == 0 ? tq : (z == 1 ? tk : tv);
  const int tx = tid & 31, ty = tid >> 5;
  int x = bx * 32 + tx;
  int y0 = by * 32;
  #pragma unroll
  for (int j = ty; j < 32; j += 8) tile[j][tx] = W[(size_t)(y0 + j) * F_ + x];
  __syncthreads();
  int x2 = y0 + tx;
  int y2 = bx * 32;
  #pragma unroll
  for (int j = ty; j < 32; j += 8) T[(size_t)(y2 + j) * F_ + x2] = f2bf(tile[tx][j]);
}

// ---------------- 2. QKV GEMM: 128x128 tile, BK=32, 4 waves ----------------
// (unchanged: swizzled staging + coalesced Q/K epilogue)
__global__ __launch_bounds__(256) void gemm_qkv(
    const short* __restrict__ Xb,
    const short* __restrict__ Wtq, const short* __restrict__ Wtk, const short* __restrict__ Wtv,
    short* __restrict__ Qb, short* __restrict__ Kb, short* __restrict__ Vt) {
  __shared__ short SMEM[4][4096];   // [0..1] = A dbuf, [2..3] = B dbuf; 32KB
  const int z = blockIdx.z;
  const short* Wt = z == 0 ? Wtq : (z == 1 ? Wtk : Wtv);
  const int m0 = blockIdx.x * 128, n0 = blockIdx.y * 128;
  const int tid = threadIdx.x, wid = tid >> 6, lane = tid & 63;
  const int wm = wid >> 1, wn = wid & 1;
  const int l15 = lane & 15, l4 = lane >> 4;

  f32x4 acc[4][4];
  #pragma unroll
  for (int i = 0; i < 4; ++i)
    #pragma unroll
    for (int j = 0; j < 4; ++j) acc[i][j] = {0.f, 0.f, 0.f, 0.f};

  const int srow = wid * 32 + (lane >> 2);
  const int scol = ((lane & 3) ^ ((lane >> 3) & 3)) * 8;
  const int rchunk = ((l15 >> 1) & 3);

  auto stage = [&](int buf, int k0) {
    gl2lds16(Xb + (size_t)(m0 + srow) * F_ + k0 + scol,      &SMEM[buf][(wid * 32) * 32]);
    gl2lds16(Xb + (size_t)(m0 + srow + 16) * F_ + k0 + scol, &SMEM[buf][(wid * 32 + 16) * 32]);
    gl2lds16(Wt + (size_t)(n0 + srow) * F_ + k0 + scol,      &SMEM[2 + buf][(wid * 32) * 32]);
    gl2lds16(Wt + (size_t)(n0 + srow + 16) * F_ + k0 + scol, &SMEM[2 + buf][(wid * 32 + 16) * 32]);
  };

  stage(0, 0);
  const int NT = F_ / 32;
  for (int t = 0; t < NT; ++t) {
    const int buf = t & 1;
    if (t + 1 < NT) {
      stage(buf ^ 1, (t + 1) * 32);
      VMCNT_BAR(4);
    } else {
      VMCNT_BAR(0);
    }
    bf16x8 a[4], b[4];
    const int rc = (l4 ^ rchunk) * 8;
    #pragma unroll
    for (int mf = 0; mf < 4; ++mf)
      a[mf] = *(const bf16x8*)&SMEM[buf][(wm * 64 + mf * 16 + l15) * 32 + rc];
    #pragma unroll
    for (int nf = 0; nf < 4; ++nf)
      b[nf] = *(const bf16x8*)&SMEM[2 + buf][(wn * 64 + nf * 16 + l15) * 32 + rc];
    __builtin_amdgcn_s_setprio(1);
    #pragma unroll
    for (int mf = 0; mf < 4; ++mf)
      #pragma unroll
      for (int nf = 0; nf < 4; ++nf)
        acc[mf][nf] = __builtin_amdgcn_mfma_f32_16x16x32_bf16(a[mf], b[nf], acc[mf][nf], 0, 0, 0);
    __builtin_amdgcn_s_setprio(0);
    __builtin_amdgcn_s_barrier();
    asm volatile("" ::: "memory");
  }

  const float qscale = 0.12751784477559752f;   // log2(e)/sqrt(S/H)

  if (z == 2) {
    #pragma unroll
    for (int mf = 0; mf < 4; ++mf)
      #pragma unroll
      for (int nf = 0; nf < 4; ++nf)
        #pragma unroll
        for (int r = 0; r < 4; ++r) {
          float v = acc[mf][nf][r];
          int row = m0 + wm * 64 + mf * 16 + l4 * 4 + r;
          int col = n0 + wn * 64 + nf * 16 + l15;
          int bb = row >> 11, s = row & 2047, h = col >> 6, d = col & 63;
          int s5 = s & 31;
          int sp = (s & ~31) | (((s5 >> 2) & 3) << 3) | (((s5 >> 4) & 1) << 2) | (s5 & 3);
          Vt[((size_t)(bb * H_ + h) * D_ + d) * S_ + sp] = f2bf(v);
        }
  } else {
    short* Ep = &SMEM[0][0];
    short* dstBase = (z == 0) ? Qb : Kb;
    const float qs = (z == 0) ? qscale : 1.f;
    #pragma unroll
    for (int p = 0; p < 2; ++p) {
      __syncthreads();
      if (wm == p) {
        #pragma unroll
        for (int mf = 0; mf < 4; ++mf)
          #pragma unroll
          for (int nf = 0; nf < 4; ++nf)
            #pragma unroll
            for (int r = 0; r < 4; ++r)
              Ep[(mf * 16 + l4 * 4 + r) * 136 + wn * 64 + nf * 16 + l15] =
                  f2bf(acc[mf][nf][r] * qs);
      }
      __syncthreads();
      const int rr = tid >> 2, qt = tid & 3;
      const int grow = m0 + p * 64 + rr;
      const int gcol = n0 + qt * 32;
      const int bb = grow >> 11, s = grow & 2047;
      const int h = gcol >> 6, d0 = gcol & 63;
      short* dst = dstBase + (((size_t)(bb * H_ + h) * S_ + s) * D_ + d0);
      #pragma unroll
      for (int k = 0; k < 4; ++k)
        *(bf16x8*)(dst + k * 8) = *(const bf16x8*)&Ep[rr * 136 + qt * 32 + k * 8];
    }
  }
}

// ---------------- 3. Flash attention + residual ----------------
// grid (B*H, S/128): 1024 blocks -> 4 blocks/CU (cross-block overlap of the
// barrier drain). Block 512 = 8 waves; wave owns 16 q rows (halved per-wave
// state vs QBLK=256). KVB=64, LDS 32KB.
// Swapped QK^T: S^T = mfma(A=K, B=Q); lane holds S at kv=nf*16+l4*4+r, q=l15.
// No max-subtraction (bounded logits). Per-bb fused {QK^T(2 nf) -> exp2 pack
// -> PV + l}. Row-sum l on the matrix pipe via ones A-fragment.
__global__ __launch_bounds__(512, 4) void attn_kernel(
    const short* __restrict__ Qb, const short* __restrict__ Kb, const short* __restrict__ Vt,
    const float* __restrict__ resid, float* __restrict__ out) {
  __shared__ short Ks[2][KVB][64];   // [kv][d], chunk ^= row&7   (16KB)
  __shared__ short Vs[2][D_][KVB];   // [d][kv-permuted], chunk ^= row&7 (16KB)
  const int bh = blockIdx.x;
  const int b = bh >> 4, h = bh & 15;
  const int qbase = blockIdx.y * QBLK;
  const int wid = threadIdx.x >> 6, lane = threadIdx.x & 63;
  const int l15 = lane & 15, l4 = lane >> 4;
  const short* Qp = Qb + (size_t)bh * S_ * D_;
  const short* Kp = Kb + (size_t)bh * S_ * D_;
  const short* Vp = Vt + (size_t)bh * D_ * S_;

  // Q as B-operand: col = q = l15, k = d (log2e-scaled); one 16-q group/wave
  bf16x8 bq0, bq1;
  {
    int qr = qbase + wid * 16 + l15;
    bq0 = *(const bf16x8*)&Qp[qr * D_ + l4 * 8];
    bq1 = *(const bf16x8*)&Qp[qr * D_ + 32 + l4 * 8];
  }

  // ones A-fragment for the l row-sum (row 0 = 1.0, rows 1..15 = 0)
  bf16x8 aOnes;
  {
    short onebf = (short)0x3F80;
    #pragma unroll
    for (int i = 0; i < 8; ++i) aOnes[i] = (l15 == 0) ? onebf : (short)0;
  }

  // staging: 8 waves x 8 rows; 1 gload each for K and V per tile
  const int sr = wid * 8 + (lane >> 3);
  const int ssrc = ((lane & 7) ^ (lane >> 3)) * 8;   // pre-swizzled source col

  f32x4 acc[4];      // O^T: row d = df*16+l4*4+r, col q = l15
  f32x4 accl;        // row-sum l at row 0 (lanes 0..15)
  accl = {0.f, 0.f, 0.f, 0.f};
  #pragma unroll
  for (int df = 0; df < 4; ++df) acc[df] = {0.f, 0.f, 0.f, 0.f};

  // prologue stage of tile 0
  gl2lds16(Kp + (0 + sr) * D_ + ssrc, &Ks[0][wid * 8][0]);
  gl2lds16(Vp + (size_t)sr * S_ + 0 + ssrc, &Vs[0][wid * 8][0]);

  const int NT = S_ / KVB;   // 32
  for (int t = 0; t < NT; ++t) {
    const int buf = t & 1;
    __syncthreads();   // drains staging of buf; prior reads of buf^1 done
    if (t + 1 < NT) {
      const int kv1 = (t + 1) * KVB;
      gl2lds16(Kp + (kv1 + sr) * D_ + ssrc, &Ks[buf ^ 1][wid * 8][0]);
      gl2lds16(Vp + (size_t)sr * S_ + kv1 + ssrc, &Vs[buf ^ 1][wid * 8][0]);
    }

    // ---- per-bb fused: QK^T (nf=2bb,2bb+1) -> pack -> PV + l ----
    __builtin_amdgcn_s_setprio(1);
    #pragma unroll
    for (int bb = 0; bb < 2; ++bb) {
      const int row0 = (2 * bb) * 16 + l15;
      const int row1 = (2 * bb + 1) * 16 + l15;
      bf16x8 ak00 = *(const bf16x8*)&Ks[buf][row0][(l4 ^ (row0 & 7)) * 8];
      bf16x8 ak01 = *(const bf16x8*)&Ks[buf][row0][((4 + l4) ^ (row0 & 7)) * 8];
      bf16x8 ak10 = *(const bf16x8*)&Ks[buf][row1][(l4 ^ (row1 & 7)) * 8];
      bf16x8 ak11 = *(const bf16x8*)&Ks[buf][row1][((4 + l4) ^ (row1 & 7)) * 8];
      f32x4 s0 = {0.f,0.f,0.f,0.f}, s1 = {0.f,0.f,0.f,0.f};
      s0 = __builtin_amdgcn_mfma_f32_16x16x32_bf16(ak00, bq0, s0, 0, 0, 0);
      s1 = __builtin_amdgcn_mfma_f32_16x16x32_bf16(ak10, bq0, s1, 0, 0, 0);
      s0 = __builtin_amdgcn_mfma_f32_16x16x32_bf16(ak01, bq1, s0, 0, 0, 0);
      s1 = __builtin_amdgcn_mfma_f32_16x16x32_bf16(ak11, bq1, s1, 0, 0, 0);

      bf16x8 p;
      #pragma unroll
      for (int r = 0; r < 4; ++r) {
        p[r]     = f2bf(__builtin_amdgcn_exp2f(s0[r]));
        p[4 + r] = f2bf(__builtin_amdgcn_exp2f(s1[r]));
      }
      #pragma unroll
      for (int df = 0; df < 4; ++df) {
        int row = df * 16 + l15;
        bf16x8 av = *(const bf16x8*)&Vs[buf][row][((4 * bb + l4) ^ (row & 7)) * 8];
        acc[df] = __builtin_amdgcn_mfma_f32_16x16x32_bf16(av, p, acc[df], 0, 0, 0);
      }
      accl = __builtin_amdgcn_mfma_f32_16x16x32_bf16(aOnes, p, accl, 0, 0, 0);
    }
    __builtin_amdgcn_s_setprio(0);
  }

  {
    float lg = __shfl(accl[0], l15);   // l for q=l15 lives at lane l15 (row 0)
    float rl = 1.f / lg;
    int s = qbase + wid * 16 + l15;
    #pragma unroll
    for (int df = 0; df < 4; ++df) {
      size_t oi = ((size_t)b * S_ + s) * F_ + h * D_ + df * 16 + l4 * 4;
      f32x4 rv = *(const f32x4*)&resid[oi];
      f32x4 ov;
      #pragma unroll
      for (int r = 0; r < 4; ++r) ov[r] = acc[df][r] * rl + rv[r];
      *(f32x4*)&out[oi] = ov;
      *(f32x4*)&out[oi + OUTHALF] = ov;
    }
  }
}

// ---------------- launch ----------------
extern "C" void kernel_launch(void* const* d_in, const int* in_sizes, int n_in,
                              void* d_out, int out_size, void* d_ws, size_t ws_size,
                              hipStream_t stream) {
  (void)in_sizes; (void)n_in; (void)out_size; (void)ws_size;
  const float* X     = (const float*)d_in[0];
  const float* resid = (const float*)d_in[1];
  const float* wq    = (const float*)d_in[2];
  const float* wk    = (const float*)d_in[3];
  const float* wv    = (const float*)d_in[4];
  float* out = (float*)d_out;
  char* ws = (char*)d_ws;
  short* Xb  = (short*)(ws);                       // 16 MB
  short* Wtq = (short*)(ws + (16u << 20));         // 2 MB
  short* Wtk = (short*)(ws + (18u << 20));         // 2 MB
  short* Wtv = (short*)(ws + (20u << 20));         // 2 MB
  short* Qb  = (short*)(ws + (22u << 20));         // 16 MB
  short* Kb  = (short*)(ws + (38u << 20));         // 16 MB
  short* Vt  = (short*)(ws + (54u << 20));         // 16 MB

  prep<<<dim3((M_ * F_) / (256 * 8) + 3 * 1024), 256, 0, stream>>>(
      X, Xb, wq, wk, wv, Wtq, Wtk, Wtv);
  gemm_qkv<<<dim3(M_ / 128, F_ / 128, 3), 256, 0, stream>>>(Xb, Wtq, Wtk, Wtv, Qb, Kb, Vt);
  attn_kernel<<<dim3(B_ * H_, S_ / QBLK), 512, 0, stream>>>(Qb, Kb, Vt, resid, out);
}

// Round 19
// 166.952 us; speedup vs baseline: 1.0737x; 1.0737x over previous
//
#include <hip/hip_runtime.h>
#include <hip/hip_bf16.h>
#include <stdint.h>

// Problem constants (B,S,F,H,D) = (4, 2048, 1024, 16, 64)
#define B_ 4
#define S_ 2048
#define F_ 1024
#define H_ 16
#define D_ 64
#define M_ (B_*S_)
#define OUTHALF ((size_t)B_*S_*F_)
#define KVB 128
#define QBLK 256   // 8 waves x 32 q-rows

typedef __attribute__((ext_vector_type(4))) float f32x4;
typedef __attribute__((ext_vector_type(8))) short bf16x8;

__device__ __forceinline__ short f2bf(float f) {
  __hip_bfloat16 h = __float2bfloat16(f);   // RNE
  return *reinterpret_cast<short*>(&h);
}

__device__ __forceinline__ void gl2lds16(const short* g, short* l) {
  __builtin_amdgcn_global_load_lds(
      (const __attribute__((address_space(1))) uint32_t*)g,
      (__attribute__((address_space(3))) uint32_t*)l, 16, 0, 0);
}

// counted-vmcnt barrier: leave N vmem ops in flight across the barrier (T4)
#define VMCNT_BAR(N)                                            \
  do {                                                          \
    asm volatile("s_waitcnt vmcnt(" #N ")" ::: "memory");       \
    __builtin_amdgcn_s_barrier();                               \
    asm volatile("" ::: "memory");                              \
  } while (0)

// ---------------- 1. Fused prep: X fp32->bf16  +  W^T bf16 ----------------
__global__ __launch_bounds__(256) void prep(
    const float* __restrict__ X, short* __restrict__ Xb,
    const float* __restrict__ wq, const float* __restrict__ wk, const float* __restrict__ wv,
    short* __restrict__ tq, short* __restrict__ tk, short* __restrict__ tv) {
  __shared__ float tile[32][33];
  const int bid = blockIdx.x;
  const int tid = threadIdx.x;
  if (bid < (M_ * F_) / (256 * 8)) {
    int i = (bid * 256 + tid) * 8;
    f32x4 a = *(const f32x4*)(X + i);
    f32x4 b = *(const f32x4*)(X + i + 4);
    bf16x8 o;
    o[0]=f2bf(a[0]); o[1]=f2bf(a[1]); o[2]=f2bf(a[2]); o[3]=f2bf(a[3]);
    o[4]=f2bf(b[0]); o[5]=f2bf(b[1]); o[6]=f2bf(b[2]); o[7]=f2bf(b[3]);
    *(bf16x8*)(Xb + i) = o;
    return;
  }
  const int b2 = bid - (M_ * F_) / (256 * 8);
  const int z = b2 >> 10;
  const int rem = b2 & 1023;
  const int bx = rem & 31, by = rem >> 5;
  const float* W = z == 0 ? wq : (z == 1 ? wk : wv);
  short* T = z == 0 ? tq : (z == 1 ? tk : tv);
  const int tx = tid & 31, ty = tid >> 5;
  int x = bx * 32 + tx;
  int y0 = by * 32;
  #pragma unroll
  for (int j = ty; j < 32; j += 8) tile[j][tx] = W[(size_t)(y0 + j) * F_ + x];
  __syncthreads();
  int x2 = y0 + tx;
  int y2 = bx * 32;
  #pragma unroll
  for (int j = ty; j < 32; j += 8) T[(size_t)(y2 + j) * F_ + x2] = f2bf(tile[tx][j]);
}

// ---------------- 2. QKV GEMM: 128x128 tile, BK=32, 4 waves ----------------
// swizzled staging (chunk ^= (row>>1)&3 both sides) + coalesced Q/K epilogue
__global__ __launch_bounds__(256) void gemm_qkv(
    const short* __restrict__ Xb,
    const short* __restrict__ Wtq, const short* __restrict__ Wtk, const short* __restrict__ Wtv,
    short* __restrict__ Qb, short* __restrict__ Kb, short* __restrict__ Vt) {
  __shared__ short SMEM[4][4096];   // [0..1] = A dbuf, [2..3] = B dbuf; 32KB
  const int z = blockIdx.z;
  const short* Wt = z == 0 ? Wtq : (z == 1 ? Wtk : Wtv);
  const int m0 = blockIdx.x * 128, n0 = blockIdx.y * 128;
  const int tid = threadIdx.x, wid = tid >> 6, lane = tid & 63;
  const int wm = wid >> 1, wn = wid & 1;
  const int l15 = lane & 15, l4 = lane >> 4;

  f32x4 acc[4][4];
  #pragma unroll
  for (int i = 0; i < 4; ++i)
    #pragma unroll
    for (int j = 0; j < 4; ++j) acc[i][j] = {0.f, 0.f, 0.f, 0.f};

  const int srow = wid * 32 + (lane >> 2);
  const int scol = ((lane & 3) ^ ((lane >> 3) & 3)) * 8;
  const int rchunk = ((l15 >> 1) & 3);

  auto stage = [&](int buf, int k0) {
    gl2lds16(Xb + (size_t)(m0 + srow) * F_ + k0 + scol,      &SMEM[buf][(wid * 32) * 32]);
    gl2lds16(Xb + (size_t)(m0 + srow + 16) * F_ + k0 + scol, &SMEM[buf][(wid * 32 + 16) * 32]);
    gl2lds16(Wt + (size_t)(n0 + srow) * F_ + k0 + scol,      &SMEM[2 + buf][(wid * 32) * 32]);
    gl2lds16(Wt + (size_t)(n0 + srow + 16) * F_ + k0 + scol, &SMEM[2 + buf][(wid * 32 + 16) * 32]);
  };

  stage(0, 0);
  const int NT = F_ / 32;
  for (int t = 0; t < NT; ++t) {
    const int buf = t & 1;
    if (t + 1 < NT) {
      stage(buf ^ 1, (t + 1) * 32);
      VMCNT_BAR(4);
    } else {
      VMCNT_BAR(0);
    }
    bf16x8 a[4], b[4];
    const int rc = (l4 ^ rchunk) * 8;
    #pragma unroll
    for (int mf = 0; mf < 4; ++mf)
      a[mf] = *(const bf16x8*)&SMEM[buf][(wm * 64 + mf * 16 + l15) * 32 + rc];
    #pragma unroll
    for (int nf = 0; nf < 4; ++nf)
      b[nf] = *(const bf16x8*)&SMEM[2 + buf][(wn * 64 + nf * 16 + l15) * 32 + rc];
    __builtin_amdgcn_s_setprio(1);
    #pragma unroll
    for (int mf = 0; mf < 4; ++mf)
      #pragma unroll
      for (int nf = 0; nf < 4; ++nf)
        acc[mf][nf] = __builtin_amdgcn_mfma_f32_16x16x32_bf16(a[mf], b[nf], acc[mf][nf], 0, 0, 0);
    __builtin_amdgcn_s_setprio(0);
    __builtin_amdgcn_s_barrier();
    asm volatile("" ::: "memory");
  }

  const float qscale = 0.12751784477559752f;   // log2(e)/sqrt(S/H)

  if (z == 2) {
    #pragma unroll
    for (int mf = 0; mf < 4; ++mf)
      #pragma unroll
      for (int nf = 0; nf < 4; ++nf)
        #pragma unroll
        for (int r = 0; r < 4; ++r) {
          float v = acc[mf][nf][r];
          int row = m0 + wm * 64 + mf * 16 + l4 * 4 + r;
          int col = n0 + wn * 64 + nf * 16 + l15;
          int bb = row >> 11, s = row & 2047, h = col >> 6, d = col & 63;
          int s5 = s & 31;
          int sp = (s & ~31) | (((s5 >> 2) & 3) << 3) | (((s5 >> 4) & 1) << 2) | (s5 & 3);
          Vt[((size_t)(bb * H_ + h) * D_ + d) * S_ + sp] = f2bf(v);
        }
  } else {
    short* Ep = &SMEM[0][0];
    short* dstBase = (z == 0) ? Qb : Kb;
    const float qs = (z == 0) ? qscale : 1.f;
    #pragma unroll
    for (int p = 0; p < 2; ++p) {
      __syncthreads();
      if (wm == p) {
        #pragma unroll
        for (int mf = 0; mf < 4; ++mf)
          #pragma unroll
          for (int nf = 0; nf < 4; ++nf)
            #pragma unroll
            for (int r = 0; r < 4; ++r)
              Ep[(mf * 16 + l4 * 4 + r) * 136 + wn * 64 + nf * 16 + l15] =
                  f2bf(acc[mf][nf][r] * qs);
      }
      __syncthreads();
      const int rr = tid >> 2, qt = tid & 3;
      const int grow = m0 + p * 64 + rr;
      const int gcol = n0 + qt * 32;
      const int bb = grow >> 11, s = grow & 2047;
      const int h = gcol >> 6, d0 = gcol & 63;
      short* dst = dstBase + (((size_t)(bb * H_ + h) * S_ + s) * D_ + d0);
      #pragma unroll
      for (int k = 0; k < 4; ++k)
        *(bf16x8*)(dst + k * 8) = *(const bf16x8*)&Ep[rr * 136 + qt * 32 + k * 8];
    }
  }
}

// ---------------- 3. Flash attention + residual ----------------
// grid (B*H, S/256); block 512 = 8 waves; wave owns 32 q rows. KVB=128.
// Per-bb fused {QK^T(2 nf) -> exp2 pack -> PV + l}; no indexed arrays.
// Swapped QK^T: S^T = mfma(A=K, B=Q); lane holds S at kv=nf*16+l4*4+r, q=l15.
// No max-subtraction (bounded logits). PV: K=32 MFMA over pi-permuted kv.
// Row-sum l on the matrix pipe via ones A-fragment.
__global__ __launch_bounds__(512, 4) void attn_kernel(
    const short* __restrict__ Qb, const short* __restrict__ Kb, const short* __restrict__ Vt,
    const float* __restrict__ resid, float* __restrict__ out) {
  __shared__ short Ks[2][KVB][64];    // [kv][d], chunk ^= row&7   (32KB)
  __shared__ short Vs[2][D_][KVB];    // [d][kv-permuted], chunk ^= row&15 (32KB)
  const int bh = blockIdx.x;
  const int b = bh >> 4, h = bh & 15;
  const int qbase = blockIdx.y * QBLK;
  const int wid = threadIdx.x >> 6, lane = threadIdx.x & 63;
  const int l15 = lane & 15, l4 = lane >> 4;
  const short* Qp = Qb + (size_t)bh * S_ * D_;
  const short* Kp = Kb + (size_t)bh * S_ * D_;
  const short* Vp = Vt + (size_t)bh * D_ * S_;

  // Q as B-operand: col = q = l15, k = d (log2e-scaled)
  bf16x8 bq[2][2];
  #pragma unroll
  for (int g = 0; g < 2; ++g) {
    int qr = qbase + wid * 32 + g * 16 + l15;
    bq[g][0] = *(const bf16x8*)&Qp[qr * D_ + l4 * 8];
    bq[g][1] = *(const bf16x8*)&Qp[qr * D_ + 32 + l4 * 8];
  }

  // ones A-fragment for the l row-sum (row 0 = 1.0, rows 1..15 = 0)
  bf16x8 aOnes;
  {
    short onebf = (short)0x3F80;
    #pragma unroll
    for (int i = 0; i < 8; ++i) aOnes[i] = (l15 == 0) ? onebf : (short)0;
  }

  // K staging: 128 rows of 64 (8 chunks); 2 calls x 8 rows/wave
  const int ksr = wid * 16 + (lane >> 3);
  const int ksc = ((lane & 7) ^ (ksr & 7)) * 8;
  // V staging: 64 rows of 128 (16 chunks); 2 calls x 4 rows/wave
  const int vr = wid * 4 + (lane >> 4);
  const int vsc = ((lane & 15) ^ (vr & 15)) * 8;

  f32x4 acc[2][4];   // O^T: row d = df*16+l4*4+r, col q = l15
  f32x4 accl[2];     // row-sum l at row 0 (lanes 0..15)
  #pragma unroll
  for (int g = 0; g < 2; ++g) {
    accl[g] = {0.f, 0.f, 0.f, 0.f};
    #pragma unroll
    for (int df = 0; df < 4; ++df) acc[g][df] = {0.f, 0.f, 0.f, 0.f};
  }

  // prologue stage of tile 0 (4 loads)
  gl2lds16(Kp + (0 + ksr) * D_ + ksc,             &Ks[0][wid * 16][0]);
  gl2lds16(Kp + (0 + ksr + 8) * D_ + ksc,         &Ks[0][wid * 16 + 8][0]);
  gl2lds16(Vp + (size_t)vr * S_ + 0 + vsc,        &Vs[0][wid * 4][0]);
  gl2lds16(Vp + (size_t)(vr + 32) * S_ + 0 + vsc, &Vs[0][32 + wid * 4][0]);

  const int NT = S_ / KVB;   // 16
  for (int t = 0; t < NT; ++t) {
    const int buf = t & 1;
    __syncthreads();   // drains staging of buf; prior reads of buf^1 done
    if (t + 1 < NT) {
      const int kv1 = (t + 1) * KVB;
      gl2lds16(Kp + (kv1 + ksr) * D_ + ksc,             &Ks[buf ^ 1][wid * 16][0]);
      gl2lds16(Kp + (kv1 + ksr + 8) * D_ + ksc,         &Ks[buf ^ 1][wid * 16 + 8][0]);
      gl2lds16(Vp + (size_t)vr * S_ + kv1 + vsc,        &Vs[buf ^ 1][wid * 4][0]);
      gl2lds16(Vp + (size_t)(vr + 32) * S_ + kv1 + vsc, &Vs[buf ^ 1][32 + wid * 4][0]);
    }

    // ---- per-bb fused: QK^T (nf=2bb,2bb+1) -> pack -> PV + l ----
    __builtin_amdgcn_s_setprio(1);
    #pragma unroll
    for (int bb = 0; bb < 4; ++bb) {
      const int row0 = (2 * bb) * 16 + l15;
      const int row1 = (2 * bb + 1) * 16 + l15;
      bf16x8 ak00 = *(const bf16x8*)&Ks[buf][row0][(l4 ^ (row0 & 7)) * 8];
      bf16x8 ak01 = *(const bf16x8*)&Ks[buf][row0][((4 + l4) ^ (row0 & 7)) * 8];
      bf16x8 ak10 = *(const bf16x8*)&Ks[buf][row1][(l4 ^ (row1 & 7)) * 8];
      bf16x8 ak11 = *(const bf16x8*)&Ks[buf][row1][((4 + l4) ^ (row1 & 7)) * 8];
      f32x4 s00 = {0.f,0.f,0.f,0.f}, s01 = {0.f,0.f,0.f,0.f};
      f32x4 s10 = {0.f,0.f,0.f,0.f}, s11 = {0.f,0.f,0.f,0.f};
      s00 = __builtin_amdgcn_mfma_f32_16x16x32_bf16(ak00, bq[0][0], s00, 0, 0, 0);
      s10 = __builtin_amdgcn_mfma_f32_16x16x32_bf16(ak00, bq[1][0], s10, 0, 0, 0);
      s01 = __builtin_amdgcn_mfma_f32_16x16x32_bf16(ak10, bq[0][0], s01, 0, 0, 0);
      s11 = __builtin_amdgcn_mfma_f32_16x16x32_bf16(ak10, bq[1][0], s11, 0, 0, 0);
      s00 = __builtin_amdgcn_mfma_f32_16x16x32_bf16(ak01, bq[0][1], s00, 0, 0, 0);
      s10 = __builtin_amdgcn_mfma_f32_16x16x32_bf16(ak01, bq[1][1], s10, 0, 0, 0);
      s01 = __builtin_amdgcn_mfma_f32_16x16x32_bf16(ak11, bq[0][1], s01, 0, 0, 0);
      s11 = __builtin_amdgcn_mfma_f32_16x16x32_bf16(ak11, bq[1][1], s11, 0, 0, 0);

      bf16x8 p0, p1;
      #pragma unroll
      for (int r = 0; r < 4; ++r) {
        p0[r]     = f2bf(__builtin_amdgcn_exp2f(s00[r]));
        p0[4 + r] = f2bf(__builtin_amdgcn_exp2f(s01[r]));
        p1[r]     = f2bf(__builtin_amdgcn_exp2f(s10[r]));
        p1[4 + r] = f2bf(__builtin_amdgcn_exp2f(s11[r]));
      }
      #pragma unroll
      for (int df = 0; df < 4; ++df) {
        int row = df * 16 + l15;
        bf16x8 av = *(const bf16x8*)&Vs[buf][row][((4 * bb + l4) ^ (row & 15)) * 8];
        acc[0][df] = __builtin_amdgcn_mfma_f32_16x16x32_bf16(av, p0, acc[0][df], 0, 0, 0);
        acc[1][df] = __builtin_amdgcn_mfma_f32_16x16x32_bf16(av, p1, acc[1][df], 0, 0, 0);
      }
      accl[0] = __builtin_amdgcn_mfma_f32_16x16x32_bf16(aOnes, p0, accl[0], 0, 0, 0);
      accl[1] = __builtin_amdgcn_mfma_f32_16x16x32_bf16(aOnes, p1, accl[1], 0, 0, 0);
    }
    __builtin_amdgcn_s_setprio(0);
  }

  #pragma unroll
  for (int g = 0; g < 2; ++g) {
    float lg = __shfl(accl[g][0], l15);   // l for q=l15 lives at lane l15 (row 0)
    float rl = 1.f / lg;
    int s = qbase + wid * 32 + g * 16 + l15;
    #pragma unroll
    for (int df = 0; df < 4; ++df) {
      size_t oi = ((size_t)b * S_ + s) * F_ + h * D_ + df * 16 + l4 * 4;
      f32x4 rv = *(const f32x4*)&resid[oi];
      f32x4 ov;
      #pragma unroll
      for (int r = 0; r < 4; ++r) ov[r] = acc[g][df][r] * rl + rv[r];
      *(f32x4*)&out[oi] = ov;
      *(f32x4*)&out[oi + OUTHALF] = ov;
    }
  }
}

// ---------------- launch ----------------
extern "C" void kernel_launch(void* const* d_in, const int* in_sizes, int n_in,
                              void* d_out, int out_size, void* d_ws, size_t ws_size,
                              hipStream_t stream) {
  (void)in_sizes; (void)n_in; (void)out_size; (void)ws_size;
  const float* X     = (const float*)d_in[0];
  const float* resid = (const float*)d_in[1];
  const float* wq    = (const float*)d_in[2];
  const float* wk    = (const float*)d_in[3];
  const float* wv    = (const float*)d_in[4];
  float* out = (float*)d_out;
  char* ws = (char*)d_ws;
  short* Xb  = (short*)(ws);                       // 16 MB
  short* Wtq = (short*)(ws + (16u << 20));         // 2 MB
  short* Wtk = (short*)(ws + (18u << 20));         // 2 MB
  short* Wtv = (short*)(ws + (20u << 20));         // 2 MB
  short* Qb  = (short*)(ws + (22u << 20));         // 16 MB
  short* Kb  = (short*)(ws + (38u << 20));         // 16 MB
  short* Vt  = (short*)(ws + (54u << 20));         // 16 MB

  prep<<<dim3((M_ * F_) / (256 * 8) + 3 * 1024), 256, 0, stream>>>(
      X, Xb, wq, wk, wv, Wtq, Wtk, Wtv);
  gemm_qkv<<<dim3(M_ / 128, F_ / 128, 3), 256, 0, stream>>>(Xb, Wtq, Wtk, Wtv, Qb, Kb, Vt);
  attn_kernel<<<dim3(B_ * H_, S_ / QBLK), 512, 0, stream>>>(Qb, Kb, Vt, resid, out);
}